// Round 9
// baseline (1033.455 us; speedup 1.0000x reference)
//
#include <hip/hip_runtime.h>
#include <hip/hip_fp16.h>

// Problem constants
#define NQ   2048      // N_LC == N_TE
#define NB   4         // batch
#define DD   256       // feature dim
#define M1   2049      // NQ + dustbin
#define STR  2064      // padded row stride (fp16 elems for E, bytes for E8/ET8, floats for u/v)
#define SINK_ITERS 100
#define PNWG 256       // persistent WGs (128 per batch-pair) — 1/CU co-residency
#define PTPB 1024      // 16 waves per WG

typedef __attribute__((ext_vector_type(8))) short short8;
typedef __attribute__((ext_vector_type(4))) float floatx4;
typedef __attribute__((ext_vector_type(2))) float floatx2;

__device__ __forceinline__ unsigned short f2bf(float f) {
  unsigned u = __float_as_uint(f);
  u += 0x7FFF + ((u >> 16) & 1);   // round-to-nearest-even
  return (unsigned short)(u >> 16);
}

// fp32 -> fp8 e5m2 (OCP): e5m2 == top byte of IEEE half, RN
__device__ __forceinline__ unsigned char f2fp8(float f) {
  unsigned short u = __half_as_ushort(__float2half(f));
  return (unsigned char)((u + 0x7F + ((u >> 8) & 1)) >> 8);
}

// swizzled LDS index: pad 1 float per 16 -> lane stride 17 floats (2-way = free)
__device__ __forceinline__ int IDX(int j) { return j + (j >> 4); }

// ---------------- merged fp32 -> bf16 convert (all 6 inputs, vec4) ----------
// total vec4 elements: 2*(NB*NQ*DD)/4 + 4*(DD*DD)/4 = 1114112 = 4352 * 256
__global__ void k_cvt6(const float* __restrict__ x_lc, const float* __restrict__ x_te,
                       const float* __restrict__ w1lc, const float* __restrict__ w2lc,
                       const float* __restrict__ w1te, const float* __restrict__ w2te,
                       unsigned short* __restrict__ Xlc, unsigned short* __restrict__ Xte,
                       unsigned short* __restrict__ Wb) {
  const int NX4 = (NB * NQ * DD) / 4;   // 524288
  const int NW4 = (DD * DD) / 4;        // 16384
  int i4 = blockIdx.x * blockDim.x + threadIdx.x;
  const float* src; unsigned short* dst; int off;
  if (i4 < NX4)            { src = x_lc; dst = Xlc; off = i4; }
  else if (i4 < 2 * NX4)   { src = x_te; dst = Xte; off = i4 - NX4; }
  else {
    int k = i4 - 2 * NX4;
    int seg = k / NW4;
    off = k - seg * NW4;
    src = (seg == 0) ? w1lc : (seg == 1) ? w2lc : (seg == 2) ? w1te : w2te;
    dst = Wb + seg * 65536;
  }
  float4 f = ((const float4*)src)[off];
  ushort4 o;
  o.x = f2bf(f.x); o.y = f2bf(f.y); o.z = f2bf(f.z); o.w = f2bf(f.w);
  ((ushort4*)dst)[off] = o;
}

// ---------------- bf16 MFMA GEMM, C = A * B^T (both [rows x K] row-major) ----
// MODE 0: +bias, relu -> bf16          (MLP layer 1; bias selected by blockIdx.z)
// MODE 1: +bias       -> bf16          (MLP layer 2; bias selected by blockIdx.z)
// MODE 2: *1/16, clamp, exp -> fp16 E AND fp8 e5m2 E8
// MODE 3: *1/16, clamp, exp -> fp8 e5m2 ET8 only
template<int MODE>
__global__ __launch_bounds__(256, 2)
void k_gemm_bt(const unsigned short* __restrict__ A,
               const unsigned short* __restrict__ Bt,
               void* __restrict__ Out, void* __restrict__ Out8,
               const float* __restrict__ bias, const float* __restrict__ bias2,
               int K, long aBatch, long bBatch, long oBatch, int ostride)
{
  __shared__ __align__(16) unsigned short lA[128 * 32];
  __shared__ __align__(16) unsigned short lB[128 * 32];
  const int tid  = threadIdx.x;
  const int lane = tid & 63;
  const int w    = tid >> 6;
  const int wm   = (w >> 1) * 64;
  const int wn   = (w & 1) * 64;
  const long bz  = blockIdx.z;
  const unsigned short* Ab = A  + bz * aBatch + (long)blockIdx.y * 128 * K;
  const unsigned short* Bb = Bt + bz * bBatch + (long)blockIdx.x * 128 * K;
  const float* bp = (bz == 0) ? bias : bias2;

  floatx4 acc[4][4];
  #pragma unroll
  for (int i = 0; i < 4; i++)
    #pragma unroll
    for (int j = 0; j < 4; j++) acc[i][j] = (floatx4){0.f, 0.f, 0.f, 0.f};

  for (int kt = 0; kt < K; kt += 32) {
    __syncthreads();
    #pragma unroll
    for (int s0 = 0; s0 < 512; s0 += 256) {
      int s = s0 + tid;
      int row = s >> 2, part = s & 3;
      ((uint4*)lA)[s] = *(const uint4*)(Ab + (long)row * K + kt + part * 8);
      ((uint4*)lB)[s] = *(const uint4*)(Bb + (long)row * K + kt + part * 8);
    }
    __syncthreads();
    const int kq = (lane >> 4) * 8;
    const int rl = lane & 15;
    short8 af[4], bf[4];
    #pragma unroll
    for (int t = 0; t < 4; t++) {
      af[t] = *(const short8*)(lA + (wm + t * 16 + rl) * 32 + kq);
      bf[t] = *(const short8*)(lB + (wn + t * 16 + rl) * 32 + kq);
    }
    #pragma unroll
    for (int i = 0; i < 4; i++)
      #pragma unroll
      for (int j = 0; j < 4; j++)
        acc[i][j] = __builtin_amdgcn_mfma_f32_16x16x32_bf16(af[i], bf[j], acc[i][j], 0, 0, 0);
  }

  // epilogue — C/D layout: col = lane&15, row = (lane>>4)*4 + reg
  const int cl = lane & 15, qd = lane >> 4;
  #pragma unroll
  for (int i = 0; i < 4; i++)
    #pragma unroll
    for (int j = 0; j < 4; j++) {
      const int col = blockIdx.x * 128 + wn + j * 16 + cl;
      const float bcol = (MODE >= 2) ? 0.f : bp[col];
      #pragma unroll
      for (int r = 0; r < 4; r++) {
        const long row = (long)blockIdx.y * 128 + wm + i * 16 + qd * 4 + r;
        float v = acc[i][j][r];
        if (MODE == 0) {
          v += bcol; v = v > 0.f ? v : 0.f;
          ((unsigned short*)Out)[bz * oBatch + row * ostride + col] = f2bf(v);
        } else if (MODE == 1) {
          v += bcol;
          ((unsigned short*)Out)[bz * oBatch + row * ostride + col] = f2bf(v);
        } else {
          v *= 0.0625f;                       // 1/sqrt(256)
          v = fminf(fmaxf(v, -15.f), 10.9f);  // e^10.9 = 54k < e5m2 max 57344
          float e = __expf(v);
          const long idx = bz * oBatch + row * ostride + col;
          if (MODE == 2) ((__half*)Out)[idx] = __float2half(e);
          ((unsigned char*)Out8)[idx] = f2fp8(e);
        }
      }
    }
}

// ---------------- fill E dustbin row/col + init ev = 1 + zero barrier --------
__global__ void k_fillinit(__half* __restrict__ E, const float* __restrict__ alphaPtr,
                           float* __restrict__ ev, unsigned* __restrict__ bar) {
  const float ea = __expf(*alphaPtr);
  const int idx = blockIdx.x * blockDim.x + threadIdx.x;
  const int n1 = NB * NQ * 16;  // rows 0..2047, cols 2048..2063
  if (idx < n1) {
    int b = idx / (NQ * 16);
    int rr = idx - b * NQ * 16;
    int i = rr >> 4;
    int j = 2048 + (rr & 15);
    E[((long)b * M1 + i) * STR + j] = (j == 2048) ? __float2half(ea) : __float2half(0.f);
  } else {
    int k = idx - n1;             // dustbin row: NB * STR entries
    if (k < NB * STR) {
      int b = k / STR;
      int j = k - b * STR;
      E[((long)b * M1 + 2048) * STR + j] = (j <= 2048) ? __float2half(ea) : __float2half(0.f);
    }
  }
  if (idx < NB * STR) ev[idx] = 1.0f;
  if (idx < 2048) bar[idx] = 0u;   // 4 batches x {cnt, gen} on separate 128B lines
}

// ---------------- agent-scope relaxed helpers (NO cache invalidates) ---------
__device__ __forceinline__ void st_agent(float* p, float v) {
  __hip_atomic_store(p, v, __ATOMIC_RELAXED, __HIP_MEMORY_SCOPE_AGENT);
}
__device__ __forceinline__ float ld_agent(const float* p) {
  return __hip_atomic_load(p, __ATOMIC_RELAXED, __HIP_MEMORY_SCOPE_AGENT);
}
__device__ __forceinline__ unsigned ld_u32_agent(const unsigned* p) {
  return __hip_atomic_load(p, __ATOMIC_RELAXED, __HIP_MEMORY_SCOPE_AGENT);
}

__device__ __forceinline__ float wave_sum(float s) {
  #pragma unroll
  for (int o = 32; o; o >>= 1) s += __shfl_xor(s, o);
  return s;
}

// dot of 16 fp8(e5m2) values with 16 fp32 weights at wp[0..15]
__device__ __forceinline__ float dot16f8(uint4 hv, const float* wp) {
  const unsigned* u = (const unsigned*)&hv;
  float s = 0.f;
#if __has_builtin(__builtin_amdgcn_cvt_pk_f32_bf8)
  #pragma unroll
  for (int q = 0; q < 4; q++) {
    floatx2 lo = __builtin_amdgcn_cvt_pk_f32_bf8((int)u[q], false);
    floatx2 hi = __builtin_amdgcn_cvt_pk_f32_bf8((int)u[q], true);
    s += lo.x * wp[q * 4 + 0] + lo.y * wp[q * 4 + 1]
       + hi.x * wp[q * 4 + 2] + hi.y * wp[q * 4 + 3];
  }
#else
  const unsigned char* p = (const unsigned char*)&hv;
  #pragma unroll
  for (int t = 0; t < 16; t++) {
    unsigned short h = (unsigned short)p[t] << 8;
    s += __half2float(*reinterpret_cast<__half*>(&h)) * wp[t];
  }
#endif
  return s;
}

// ---------------- persistent Sinkhorn, plain launch (NOT cooperative) --------
// R9: BATCH-PAIR INTERLEAVE. Each WG serves TWO batches (pair p = wg>>7:
// batches 2p, 2p+1), 128 WGs per batch, 1 row per wave per matrix per batch.
// While batch A's barrier propagates (~0.6-0.9us: RMW + gen + observe), the
// WG stages+computes batch B (~1-1.4us) — the barrier leaves the critical
// path. R8 exposed that wait (tid0 idle 1.5-1.8us/phase at VALUBusy 31%).
//
// Sync per batch = R6 protocol, 128 arrivals: monotone cnt fetch_add; last
// man (old == 128*(hp+1)-1) broadcasts gen on a separate 128B line. Arrive
// and poll run on DIFFERENT waves concurrently (tid64 arrives, tid0 polls)
// so the RMW latency overlaps the poll. gen semantics: genX = n means batch
// X's half-phases 0..n-1 complete; consuming half-phase hp's input requires
// genX >= hp (hp=0 input is the k_fillinit ev=1 vector — no wait).
//
// Rows LDS-pinned (R8 win): 16 waves x (A:E8,ET8 + B:E8,ET8) x 2KB = 128KB,
// + 2 x 8.8KB staged vectors = 145KB < 160KB -> 1 WG/CU, grid 256 = CU count.
// Codegen shape rules preserved: no lambda, scalar sync ops on tid0/tid64
// only, row reads after the staging sync, stage loop shape unchanged.
__global__ __launch_bounds__(PTPB, 4)
void k_sink(const unsigned char* __restrict__ E8, const unsigned char* __restrict__ ET8,
            float* __restrict__ eu, float* __restrict__ ev,
            const float* __restrict__ alphaPtr, unsigned* __restrict__ bar)
{
  __shared__ __align__(16) unsigned char rows[131072];  // [wave][A-E8|A-ET8|B-E8|B-ET8][2048]
  __shared__ __align__(16) float svA[2200];             // staged A vector (swizzled)
  __shared__ __align__(16) float svB[2200];             // staged B vector (swizzled)
  const int tid  = threadIdx.x;
  const int wg   = blockIdx.x;
  const int p    = wg >> 7;          // pair 0: batches 0,1; pair 1: batches 2,3
  const int g    = wg & 127;         // group within pair
  const int wv   = tid >> 6;         // wave 0..15
  const int lane = tid & 63;
  const int r    = g * 16 + wv;      // this wave's row in [0, 2048)
  const float ea = __expf(alphaPtr[0]);
  const int bA = p * 2, bB = p * 2 + 1;
  float* uA = eu + bA * STR;  float* vA = ev + bA * STR;
  float* uB = eu + bB * STR;  float* vB = ev + bB * STR;
  unsigned* cntA = bar + bA * 64;  unsigned* genA = cntA + 32;
  unsigned* cntB = bar + bB * 64;  unsigned* genB = cntB + 32;
  const bool dustw = (g == 127) && (wv == 15);

  // prologue: pin this wave's 4 rows in LDS (each row read once from L2/HBM)
  {
    uint4* dw = (uint4*)(rows + wv * 8192);
    const unsigned char* pA  = E8  + ((long)bA * M1 + r) * STR;
    const unsigned char* pAT = ET8 + ((long)bA * M1 + r) * STR;
    const unsigned char* pB  = E8  + ((long)bB * M1 + r) * STR;
    const unsigned char* pBT = ET8 + ((long)bB * M1 + r) * STR;
    dw[lane]       = *(const uint4*)(pA  +        lane * 16);
    dw[64 + lane]  = *(const uint4*)(pA  + 1024 + lane * 16);
    dw[128 + lane] = *(const uint4*)(pAT +        lane * 16);
    dw[192 + lane] = *(const uint4*)(pAT + 1024 + lane * 16);
    dw[256 + lane] = *(const uint4*)(pB  +        lane * 16);
    dw[320 + lane] = *(const uint4*)(pB  + 1024 + lane * 16);
    dw[384 + lane] = *(const uint4*)(pBT +        lane * 16);
    dw[448 + lane] = *(const uint4*)(pBT + 1024 + lane * 16);
  }

  const float* w0A = svA + lane * 17;          // IDX(lane*16)
  const float* w1A = svA + 1088 + lane * 17;   // IDX(1024 + lane*16)
  const float* w0B = svB + lane * 17;
  const float* w1B = svB + 1088 + lane * 17;

  for (int hp = 0; hp < 2 * SINK_ITERS; ++hp) {
    const unsigned hpu = (unsigned)hp;
    const float* vinA = (hp & 1) ? uA : vA;
    float*      voutA = (hp & 1) ? vA : uA;
    const float* vinB = (hp & 1) ? uB : vB;
    float*      voutB = (hp & 1) ? vB : uB;

    // ---- P1: tid64 publishes B's previous half-phase; tid0 polls A input --
    if (tid == 64 && hp > 0) {
      unsigned old = __hip_atomic_fetch_add(cntB, 1u, __ATOMIC_RELAXED, __HIP_MEMORY_SCOPE_AGENT);
      if (old == hpu * 128u - 1u)
        __hip_atomic_store(genB, hpu, __ATOMIC_RELAXED, __HIP_MEMORY_SCOPE_AGENT);
    }
    if (tid == 0) {
      while (ld_u32_agent(genA) < hpu)
        __builtin_amdgcn_s_sleep(1);
    }
    __syncthreads();

    // ---- stage A vector (sc1: fresh from LLC) ----
    for (int j = tid; j < M1; j += PTPB) svA[IDX(j)] = ld_agent(vinA + j);
    __syncthreads();

    // ---- compute A: one row from the LDS row cache ----
    {
      const unsigned char* R = rows + wv * 8192 + ((hp & 1) << 11);
      uint4 c0 = *(const uint4*)(R +        lane * 16);
      uint4 c1 = *(const uint4*)(R + 1024 + lane * 16);
      float a = dot16f8(c0, w0A) + dot16f8(c1, w1A);
      a = wave_sum(a);
      if (lane == 0) {
        const float wd = ea * svA[IDX(2048)];
        st_agent(voutA + r, (1.f / 4096.f) / (a + wd));
      }
      if (dustw) {
        float s = 0.f;
        #pragma unroll
        for (int t = 0; t < 16; t++) s += w0A[t] + w1A[t];
        s = wave_sum(s);
        if (lane == 0) st_agent(voutA + 2048, 0.5f / (ea * (s + svA[IDX(2048)])));
      }
    }
    __syncthreads();   // drains vmcnt: A stores at LLC

    // ---- P2: tid64 publishes A's half-phase; tid0 polls B input ----------
    if (tid == 64) {
      unsigned old = __hip_atomic_fetch_add(cntA, 1u, __ATOMIC_RELAXED, __HIP_MEMORY_SCOPE_AGENT);
      if (old == (hpu + 1u) * 128u - 1u)
        __hip_atomic_store(genA, hpu + 1u, __ATOMIC_RELAXED, __HIP_MEMORY_SCOPE_AGENT);
    }
    if (tid == 0) {
      while (ld_u32_agent(genB) < hpu)
        __builtin_amdgcn_s_sleep(1);
    }
    __syncthreads();

    // ---- stage B vector ----
    for (int j = tid; j < M1; j += PTPB) svB[IDX(j)] = ld_agent(vinB + j);
    __syncthreads();

    // ---- compute B ----
    {
      const unsigned char* R = rows + wv * 8192 + 4096 + ((hp & 1) << 11);
      uint4 c0 = *(const uint4*)(R +        lane * 16);
      uint4 c1 = *(const uint4*)(R + 1024 + lane * 16);
      float a = dot16f8(c0, w0B) + dot16f8(c1, w1B);
      a = wave_sum(a);
      if (lane == 0) {
        const float wd = ea * svB[IDX(2048)];
        st_agent(voutB + r, (1.f / 4096.f) / (a + wd));
      }
      if (dustw) {
        float s = 0.f;
        #pragma unroll
        for (int t = 0; t < 16; t++) s += w0B[t] + w1B[t];
        s = wave_sum(s);
        if (lane == 0) st_agent(voutB + 2048, 0.5f / (ea * (s + svB[IDX(2048)])));
      }
    }
    __syncthreads();   // drains vmcnt: B stores at LLC (published at next P1)
  }
  // final B half-phase never published: k_final is stream-ordered (kernel
  // completion is the fence) — no reader polls genB >= 200.
}

// ---------------- finalize: out = E * eu * ev * 4096 (fp16 E) ----------------
__global__ void k_final(const __half* __restrict__ E, const float* __restrict__ eu,
                        const float* __restrict__ ev, float* __restrict__ out) {
  const int wv = blockIdx.x;      // NB * M1 rows
  const int b = wv / M1;
  const int i = wv - b * M1;
  const __half* R = E + ((long)b * M1 + i) * STR;
  const float ui = eu[b * STR + i] * 4096.f;   // * exp(-norm)
  const float* evb = ev + b * STR;
  float* orow = out + ((long)b * M1 + i) * M1;
  for (int j = threadIdx.x; j < M1; j += blockDim.x)
    orow[j] = __half2float(R[j]) * ui * evb[j];
}

// ---------------- launch -----------------------------------------------------
extern "C" void kernel_launch(void* const* d_in, const int* in_sizes, int n_in,
                              void* d_out, int out_size, void* d_ws, size_t ws_size,
                              hipStream_t stream) {
  const float* x_lc  = (const float*)d_in[0];
  const float* x_te  = (const float*)d_in[1];
  const float* W1_lc = (const float*)d_in[2];
  const float* b1_lc = (const float*)d_in[3];
  const float* W2_lc = (const float*)d_in[4];
  const float* b2_lc = (const float*)d_in[5];
  const float* W1_te = (const float*)d_in[6];
  const float* b1_te = (const float*)d_in[7];
  const float* W2_te = (const float*)d_in[8];
  const float* b2_te = (const float*)d_in[9];
  const float* alpha = (const float*)d_in[10];

  char* ws = (char*)d_ws;
  unsigned short* Xlc = (unsigned short*)(ws + 0);          //  4 MB (later reused as F1)
  unsigned short* Wb  = (unsigned short*)(ws + 8388608);    //  0.5 MB
  unsigned short* H   = (unsigned short*)(ws + 8912896);    //  8 MB (both MLP chains)
  unsigned short* F   = (unsigned short*)(ws + 0);          //  8 MB (F1 @0, F2 @4MB)
  __half* E  = (__half*)(ws + 21495808);                    // 33.83 MB fp16 (final)
  unsigned char* E8  = (unsigned char*)(ws + 55328896);     // 16.92 MB fp8 (sweep)
  unsigned char* ET8 = (unsigned char*)(ws + 72245440);     // 16.92 MB fp8 (sweep)
  float* eu  = (float*)(ws + 89161984);                     // 4 x 2064 f32
  float* ev  = (float*)(ws + 89195008);                     // 4 x 2064 f32
  unsigned* bar = (unsigned*)(ws + 89228032);               // 8 KB barrier state

  unsigned short* Xte = Xlc + 2097152;   // ws + 4 MB

  // merged fp32->bf16 conversion of all six inputs (one launch, vec4)
  k_cvt6<<<4352, 256, 0, stream>>>(x_lc, x_te, W1_lc, W2_lc, W1_te, W2_te,
                                   Xlc, Xte, Wb);

  // MLPs: lc and te chains merged via blockIdx.z (z=0: lc, z=1: te).
  k_gemm_bt<0><<<dim3(2, 64, 2), 256, 0, stream>>>(Xlc, Wb,         H, nullptr, b1_lc, b1_te,
                                                   DD, 2097152, 131072, 2097152, DD);
  k_gemm_bt<1><<<dim3(2, 64, 2), 256, 0, stream>>>(H,   Wb + 65536, F, nullptr, b2_lc, b2_te,
                                                   DD, 2097152, 131072, 2097152, DD);

  // scores -> E (fp16+fp8) and ET (fp8 only), per batch
  unsigned short* F1 = F;
  unsigned short* F2 = F + 2097152;
  const long ab = (long)NQ * DD;        // 524288
  const long ob = (long)M1 * STR;       // 4229136 (elems for fp16, bytes for fp8)
  k_gemm_bt<2><<<dim3(16, 16, NB), 256, 0, stream>>>(F1, F2, E,  E8,  nullptr, nullptr, DD, ab, ab, ob, STR);
  k_gemm_bt<3><<<dim3(16, 16, NB), 256, 0, stream>>>(F2, F1, nullptr, ET8, nullptr, nullptr, DD, ab, ab, ob, STR);

  // E dustbin row/col + ev = 1 + barrier = 0 (one launch)
  const int nfill = NB * NQ * 16 + NB * STR;  // 139328
  k_fillinit<<<(nfill + 255) / 256, 256, 0, stream>>>(E, alpha, ev, bar);

  // persistent Sinkhorn: ONE plain launch, fixed 100 iterations
  k_sink<<<PNWG, PTPB, 0, stream>>>(E8, ET8, eu, ev, alpha, bar);

  // out = E * eu * ev * (m+n)
  k_final<<<NB * M1, 256, 0, stream>>>(E, eu, ev, (float*)d_out);
}

// Round 10
// 789.018 us; speedup vs baseline: 1.3098x; 1.3098x over previous
//
#include <hip/hip_runtime.h>
#include <hip/hip_fp16.h>

// Problem constants
#define NQ   2048      // N_LC == N_TE
#define NB   4         // batch
#define DD   256       // feature dim
#define M1   2049      // NQ + dustbin
#define STR  2064      // padded row stride (fp16 elems for E, bytes for E8/ET8, floats for u/v)
#define SINK_ITERS 100
#define PNWG 256       // persistent WGs (64 per batch) — 1/CU co-residency
#define PTPB 1024      // 16 waves per WG

typedef __attribute__((ext_vector_type(8))) short short8;
typedef __attribute__((ext_vector_type(4))) float floatx4;
typedef __attribute__((ext_vector_type(2))) float floatx2;
typedef _Float16 h2 __attribute__((ext_vector_type(2)));

__device__ __forceinline__ unsigned short f2bf(float f) {
  unsigned u = __float_as_uint(f);
  u += 0x7FFF + ((u >> 16) & 1);   // round-to-nearest-even
  return (unsigned short)(u >> 16);
}

// fp32 -> fp8 e5m2 (OCP): e5m2 == top byte of IEEE half, RN
__device__ __forceinline__ unsigned char f2fp8(float f) {
  unsigned short u = __half_as_ushort(__float2half(f));
  return (unsigned char)((u + 0x7F + ((u >> 8) & 1)) >> 8);
}

__device__ __forceinline__ h2 as_h2(unsigned x) {
  union { unsigned u; h2 h; } c; c.u = x; return c.h;
}

// ---------------- merged fp32 -> bf16 convert (all 6 inputs, vec4) ----------
// total vec4 elements: 2*(NB*NQ*DD)/4 + 4*(DD*DD)/4 = 1114112 = 4352 * 256
__global__ void k_cvt6(const float* __restrict__ x_lc, const float* __restrict__ x_te,
                       const float* __restrict__ w1lc, const float* __restrict__ w2lc,
                       const float* __restrict__ w1te, const float* __restrict__ w2te,
                       unsigned short* __restrict__ Xlc, unsigned short* __restrict__ Xte,
                       unsigned short* __restrict__ Wb) {
  const int NX4 = (NB * NQ * DD) / 4;   // 524288
  const int NW4 = (DD * DD) / 4;        // 16384
  int i4 = blockIdx.x * blockDim.x + threadIdx.x;
  const float* src; unsigned short* dst; int off;
  if (i4 < NX4)            { src = x_lc; dst = Xlc; off = i4; }
  else if (i4 < 2 * NX4)   { src = x_te; dst = Xte; off = i4 - NX4; }
  else {
    int k = i4 - 2 * NX4;
    int seg = k / NW4;
    off = k - seg * NW4;
    src = (seg == 0) ? w1lc : (seg == 1) ? w2lc : (seg == 2) ? w1te : w2te;
    dst = Wb + seg * 65536;
  }
  float4 f = ((const float4*)src)[off];
  ushort4 o;
  o.x = f2bf(f.x); o.y = f2bf(f.y); o.z = f2bf(f.z); o.w = f2bf(f.w);
  ((ushort4*)dst)[off] = o;
}

// ---------------- bf16 MFMA GEMM, C = A * B^T (both [rows x K] row-major) ----
// MODE 0: +bias, relu -> bf16          (MLP layer 1; bias selected by blockIdx.z)
// MODE 1: +bias       -> bf16          (MLP layer 2; bias selected by blockIdx.z)
// MODE 2: *1/16, clamp, exp -> fp16 E AND fp8 e5m2 E8
// MODE 3: *1/16, clamp, exp -> fp8 e5m2 ET8 only
template<int MODE>
__global__ __launch_bounds__(256, 2)
void k_gemm_bt(const unsigned short* __restrict__ A,
               const unsigned short* __restrict__ Bt,
               void* __restrict__ Out, void* __restrict__ Out8,
               const float* __restrict__ bias, const float* __restrict__ bias2,
               int K, long aBatch, long bBatch, long oBatch, int ostride)
{
  __shared__ __align__(16) unsigned short lA[128 * 32];
  __shared__ __align__(16) unsigned short lB[128 * 32];
  const int tid  = threadIdx.x;
  const int lane = tid & 63;
  const int w    = tid >> 6;
  const int wm   = (w >> 1) * 64;
  const int wn   = (w & 1) * 64;
  const long bz  = blockIdx.z;
  const unsigned short* Ab = A  + bz * aBatch + (long)blockIdx.y * 128 * K;
  const unsigned short* Bb = Bt + bz * bBatch + (long)blockIdx.x * 128 * K;
  const float* bp = (bz == 0) ? bias : bias2;

  floatx4 acc[4][4];
  #pragma unroll
  for (int i = 0; i < 4; i++)
    #pragma unroll
    for (int j = 0; j < 4; j++) acc[i][j] = (floatx4){0.f, 0.f, 0.f, 0.f};

  for (int kt = 0; kt < K; kt += 32) {
    __syncthreads();
    #pragma unroll
    for (int s0 = 0; s0 < 512; s0 += 256) {
      int s = s0 + tid;
      int row = s >> 2, part = s & 3;
      ((uint4*)lA)[s] = *(const uint4*)(Ab + (long)row * K + kt + part * 8);
      ((uint4*)lB)[s] = *(const uint4*)(Bb + (long)row * K + kt + part * 8);
    }
    __syncthreads();
    const int kq = (lane >> 4) * 8;
    const int rl = lane & 15;
    short8 af[4], bf[4];
    #pragma unroll
    for (int t = 0; t < 4; t++) {
      af[t] = *(const short8*)(lA + (wm + t * 16 + rl) * 32 + kq);
      bf[t] = *(const short8*)(lB + (wn + t * 16 + rl) * 32 + kq);
    }
    #pragma unroll
    for (int i = 0; i < 4; i++)
      #pragma unroll
      for (int j = 0; j < 4; j++)
        acc[i][j] = __builtin_amdgcn_mfma_f32_16x16x32_bf16(af[i], bf[j], acc[i][j], 0, 0, 0);
  }

  // epilogue — C/D layout: col = lane&15, row = (lane>>4)*4 + reg
  const int cl = lane & 15, qd = lane >> 4;
  #pragma unroll
  for (int i = 0; i < 4; i++)
    #pragma unroll
    for (int j = 0; j < 4; j++) {
      const int col = blockIdx.x * 128 + wn + j * 16 + cl;
      const float bcol = (MODE >= 2) ? 0.f : bp[col];
      #pragma unroll
      for (int r = 0; r < 4; r++) {
        const long row = (long)blockIdx.y * 128 + wm + i * 16 + qd * 4 + r;
        float v = acc[i][j][r];
        if (MODE == 0) {
          v += bcol; v = v > 0.f ? v : 0.f;
          ((unsigned short*)Out)[bz * oBatch + row * ostride + col] = f2bf(v);
        } else if (MODE == 1) {
          v += bcol;
          ((unsigned short*)Out)[bz * oBatch + row * ostride + col] = f2bf(v);
        } else {
          v *= 0.0625f;                       // 1/sqrt(256)
          v = fminf(fmaxf(v, -15.f), 10.9f);  // e^10.9 = 54k < e5m2 max 57344
          float e = __expf(v);
          const long idx = bz * oBatch + row * ostride + col;
          if (MODE == 2) ((__half*)Out)[idx] = __float2half(e);
          ((unsigned char*)Out8)[idx] = f2fp8(e);
        }
      }
    }
}

// ---------------- fill E dustbin row/col + init ev = 1 + zero barrier --------
__global__ void k_fillinit(__half* __restrict__ E, const float* __restrict__ alphaPtr,
                           float* __restrict__ ev, unsigned* __restrict__ bar) {
  const float ea = __expf(*alphaPtr);
  const int idx = blockIdx.x * blockDim.x + threadIdx.x;
  const int n1 = NB * NQ * 16;  // rows 0..2047, cols 2048..2063
  if (idx < n1) {
    int b = idx / (NQ * 16);
    int rr = idx - b * NQ * 16;
    int i = rr >> 4;
    int j = 2048 + (rr & 15);
    E[((long)b * M1 + i) * STR + j] = (j == 2048) ? __float2half(ea) : __float2half(0.f);
  } else {
    int k = idx - n1;             // dustbin row: NB * STR entries
    if (k < NB * STR) {
      int b = k / STR;
      int j = k - b * STR;
      E[((long)b * M1 + 2048) * STR + j] = (j <= 2048) ? __float2half(ea) : __float2half(0.f);
    }
  }
  if (idx < NB * STR) ev[idx] = 1.0f;
  if (idx < 2048) bar[idx] = 0u;   // 4 batches x {cnt, gen} on separate 128B lines
}

// ---------------- agent-scope relaxed helpers (NO cache invalidates) ---------
__device__ __forceinline__ void st_agent(float* p, float v) {
  __hip_atomic_store(p, v, __ATOMIC_RELAXED, __HIP_MEMORY_SCOPE_AGENT);
}
__device__ __forceinline__ float ld_agent(const float* p) {
  return __hip_atomic_load(p, __ATOMIC_RELAXED, __HIP_MEMORY_SCOPE_AGENT);
}
__device__ __forceinline__ unsigned long long ld64_agent(const unsigned long long* p) {
  return __hip_atomic_load(p, __ATOMIC_RELAXED, __HIP_MEMORY_SCOPE_AGENT);
}
__device__ __forceinline__ unsigned ld_u32_agent(const unsigned* p) {
  return __hip_atomic_load(p, __ATOMIC_RELAXED, __HIP_MEMORY_SCOPE_AGENT);
}

__device__ __forceinline__ float wave_sum(float s) {
  #pragma unroll
  for (int o = 32; o; o >>= 1) s += __shfl_xor(s, o);
  return s;
}

// dot of 16 fp8(e5m2) row bytes (uint4) with 16 fp16 weights (8 h2 dwords).
// e5m2 -> fp16 is exact: byte<<8. v_perm builds 2 halves/dword in 1 op;
// v_dot2_f32_f16 does 2 MACs with f32 accumulate. 16 VALU per 16 elems
// (vs 24 for cvt_pk_f32_bf8 + fma).
__device__ __forceinline__ float dot16e5(uint4 hv, const unsigned* wp, float s) {
  const unsigned* u = (const unsigned*)&hv;
#if __has_builtin(__builtin_amdgcn_fdot2) && __has_builtin(__builtin_amdgcn_perm)
  #pragma unroll
  for (int q = 0; q < 4; q++) {
    unsigned lo = __builtin_amdgcn_perm(u[q], 0u, 0x05000400u);  // [0,b0, 0,b1] -> halves b0<<8, b1<<8
    unsigned hi = __builtin_amdgcn_perm(u[q], 0u, 0x07000600u);  // halves b2<<8, b3<<8
    s = __builtin_amdgcn_fdot2(as_h2(lo), as_h2(wp[2 * q]),     s, false);
    s = __builtin_amdgcn_fdot2(as_h2(hi), as_h2(wp[2 * q + 1]), s, false);
  }
#else
  const unsigned char* p = (const unsigned char*)&hv;
  #pragma unroll
  for (int t = 0; t < 16; t++) {
    unsigned short he = (unsigned short)p[t] << 8;
    unsigned wdw = wp[t >> 1];
    unsigned short hw = (t & 1) ? (unsigned short)(wdw >> 16) : (unsigned short)(wdw & 0xFFFF);
    s += __half2float(*reinterpret_cast<__half*>(&he)) *
         __half2float(*reinterpret_cast<__half*>(&hw));
  }
#endif
  return s;
}

// ---------------- persistent Sinkhorn, plain launch (NOT cooperative) --------
// R8 core (878us total): fp8 rows LDS-pinned (FETCH 43MB), 64 WGs/batch,
// R6 barrier (flat arrive + last-man gen broadcast on separate 128B line).
// Batches are already fully parallel across CUs — R9's pairing proved wall
// time = one batch's phase chain x 200. R10 shortens the chain:
//  (1) staging: ONE 8B agent load/thread (float2), x4096, fp16-pack -> one
//      LDS dword. R7's proven scaling: u ~ 1.2e-7 is fp16-subnormal; x4096
//      fixes it; formulas rescale analytically (u = 1/(a_s + ea*d_s),
//      dust = 2048/(ea*(S_s + d_s))). fp16 weights precision-proven by R7
//      (absmax identical 0.0039).
//  (2) dots: v_perm + v_dot2_f32_f16 (16 VALU/16 elems vs 24) and HALF the
//      weight LDS reads (8 b32/chunk, stride-9 dwords: gcd(9,32)=1 ->
//      conflict-free).
//  (3) tid0 prefetches gen BEFORE its arrive RMW (overlaps one LLC hop).
// Codegen shape rules preserved: no lambda, tid0-only scalar poll, row reads
// after the staging sync.
__global__ __launch_bounds__(PTPB, 4)
void k_sink(const unsigned char* __restrict__ E8, const unsigned char* __restrict__ ET8,
            float* __restrict__ eu, float* __restrict__ ev,
            const float* __restrict__ alphaPtr, unsigned* __restrict__ bar)
{
  __shared__ __align__(16) unsigned char rows[131072];  // [wave][E|ET][2 rows][2048]
  __shared__ __align__(16) unsigned svh[1160];          // 2 chunks x 576 h2-dwords (pad/8)
  __shared__ float sdust;                               // staged vin[2048] * 4096
  const int tid  = threadIdx.x;
  const int wg   = blockIdx.x;
  const int b    = wg >> 6;          // batch 0..3
  const int g    = wg & 63;          // group within batch
  const int wv   = tid >> 6;         // wave 0..15
  const int lane = tid & 63;
  const int r0   = (g * 16 + wv) * 2;   // rows r0, r0+1 in [0, 2048)
  const float ea = __expf(alphaPtr[0]);
  const unsigned char* E8r  = E8  + ((long)b * M1 + r0) * STR;
  const unsigned char* ET8r = ET8 + ((long)b * M1 + r0) * STR;
  float* ub = eu + b * STR;
  float* vb = ev + b * STR;
  unsigned* cnt = bar + b * 64;       // per-batch arrive counter
  unsigned* gen = bar + b * 64 + 32;  // release word, separate 128B line
  const bool dustwave = (g == 63) && (wv == 15);
  // staging slot: pair p = tid covers columns 2p, 2p+1; chunk = tid>>9
  const int sslot = (tid >> 9) * 576 + (tid & 511) + ((tid & 511) >> 3);

  // prologue: pin this wave's 4 rows in LDS (read once from L2/HBM)
  {
    uint4* dw = (uint4*)(rows + wv * 8192);
    dw[lane]       = *(const uint4*)(E8r  +        lane * 16);
    dw[64 + lane]  = *(const uint4*)(E8r  + 1024 + lane * 16);
    dw[128 + lane] = *(const uint4*)(E8r  + STR  +        lane * 16);
    dw[192 + lane] = *(const uint4*)(E8r  + STR  + 1024 + lane * 16);
    dw[256 + lane] = *(const uint4*)(ET8r +        lane * 16);
    dw[320 + lane] = *(const uint4*)(ET8r + 1024 + lane * 16);
    dw[384 + lane] = *(const uint4*)(ET8r + STR  +        lane * 16);
    dw[448 + lane] = *(const uint4*)(ET8r + STR  + 1024 + lane * 16);
  }

  const unsigned* w0 = svh + 9 * lane;          // chunk 0: lane's 8 h2 dwords
  const unsigned* w1 = svh + 576 + 9 * lane;    // chunk 1
  const unsigned ONES2 = 0x3C003C00u;           // fp16 (1.0, 1.0)

  unsigned phase = 0;
  for (int it = 0; it < 2 * SINK_ITERS; ++it) {
    const float* vin = (it & 1) ? ub : vb;
    float*      vout = (it & 1) ? vb : ub;

    // stage vin*4096 -> packed fp16 pairs in LDS (one 8B sc1 load per thread)
    {
      unsigned long long w8 = ld64_agent((const unsigned long long*)(vin + 2 * tid));
      float flo = __uint_as_float((unsigned)w8) * 4096.f;
      float fhi = __uint_as_float((unsigned)(w8 >> 32)) * 4096.f;
      unsigned pk = ((unsigned)__half_as_ushort(__float2half(fhi)) << 16)
                  |  (unsigned)__half_as_ushort(__float2half(flo));
      svh[sslot] = pk;
      if (tid == 0) sdust = ld_agent(vin + 2048) * 4096.f;
    }
    __syncthreads();

    // two fp8 rows per wave from the LDS row cache
    const unsigned char* Rl = rows + wv * 8192 + ((it & 1) << 12);
    uint4 h0c0 = *(const uint4*)(Rl +        lane * 16);
    uint4 h0c1 = *(const uint4*)(Rl + 1024 + lane * 16);
    uint4 h1c0 = *(const uint4*)(Rl + 2048 + lane * 16);
    uint4 h1c1 = *(const uint4*)(Rl + 3072 + lane * 16);
    float a0 = dot16e5(h0c1, w1, dot16e5(h0c0, w0, 0.f));
    float a1 = dot16e5(h1c1, w1, dot16e5(h1c0, w0, 0.f));
    a0 = wave_sum(a0);
    a1 = wave_sum(a1);
    if (lane == 0) {
      const float wd = ea * sdust;               // dustbin column (scaled)
      st_agent(vout + r0,     1.f / (a0 + wd));
      st_agent(vout + r0 + 1, 1.f / (a1 + wd));
    }

    // dustbin row analytic: vout[2048] = 2048 / (ea * (S_s + d_s))
    if (dustwave) {
      float s = 0.f;
#if __has_builtin(__builtin_amdgcn_fdot2)
      #pragma unroll
      for (int k = 0; k < 8; k++) s = __builtin_amdgcn_fdot2(as_h2(w0[k]), as_h2(ONES2), s, false);
      #pragma unroll
      for (int k = 0; k < 8; k++) s = __builtin_amdgcn_fdot2(as_h2(w1[k]), as_h2(ONES2), s, false);
#else
      #pragma unroll
      for (int k = 0; k < 8; k++) {
        unsigned a = w0[k], c = w1[k];
        unsigned short x0 = (unsigned short)a, x1 = (unsigned short)(a >> 16);
        unsigned short y0 = (unsigned short)c, y1 = (unsigned short)(c >> 16);
        s += __half2float(*reinterpret_cast<__half*>(&x0)) + __half2float(*reinterpret_cast<__half*>(&x1))
           + __half2float(*reinterpret_cast<__half*>(&y0)) + __half2float(*reinterpret_cast<__half*>(&y1));
      }
#endif
      s = wave_sum(s);
      if (lane == 0) st_agent(vout + 2048, 2048.f / (ea * (s + sdust)));
    }

    // ---- per-batch barrier: flat arrive + last-man gen broadcast ----
    ++phase;
    __syncthreads();   // drains vmcnt: this WG's sc1 stores are at LLC
    if (tid == 0) {
      unsigned gpre = ld_u32_agent(gen);   // prefetch: overlaps the RMW hop
      unsigned old = __hip_atomic_fetch_add(cnt, 1u, __ATOMIC_RELAXED, __HIP_MEMORY_SCOPE_AGENT);
      if (old == phase * 64u - 1u) {
        __hip_atomic_store(gen, phase, __ATOMIC_RELAXED, __HIP_MEMORY_SCOPE_AGENT);
      } else {
        while (gpre < phase) {
          __builtin_amdgcn_s_sleep(1);
          gpre = ld_u32_agent(gen);
        }
      }
    }
    __syncthreads();
  }
}

// ---------------- finalize: out = E * eu * ev * 4096 (fp16 E) ----------------
__global__ void k_final(const __half* __restrict__ E, const float* __restrict__ eu,
                        const float* __restrict__ ev, float* __restrict__ out) {
  const int wv = blockIdx.x;      // NB * M1 rows
  const int b = wv / M1;
  const int i = wv - b * M1;
  const __half* R = E + ((long)b * M1 + i) * STR;
  const float ui = eu[b * STR + i] * 4096.f;   // * exp(-norm)
  const float* evb = ev + b * STR;
  float* orow = out + ((long)b * M1 + i) * M1;
  for (int j = threadIdx.x; j < M1; j += blockDim.x)
    orow[j] = __half2float(R[j]) * ui * evb[j];
}

// ---------------- launch -----------------------------------------------------
extern "C" void kernel_launch(void* const* d_in, const int* in_sizes, int n_in,
                              void* d_out, int out_size, void* d_ws, size_t ws_size,
                              hipStream_t stream) {
  const float* x_lc  = (const float*)d_in[0];
  const float* x_te  = (const float*)d_in[1];
  const float* W1_lc = (const float*)d_in[2];
  const float* b1_lc = (const float*)d_in[3];
  const float* W2_lc = (const float*)d_in[4];
  const float* b2_lc = (const float*)d_in[5];
  const float* W1_te = (const float*)d_in[6];
  const float* b1_te = (const float*)d_in[7];
  const float* W2_te = (const float*)d_in[8];
  const float* b2_te = (const float*)d_in[9];
  const float* alpha = (const float*)d_in[10];

  char* ws = (char*)d_ws;
  unsigned short* Xlc = (unsigned short*)(ws + 0);          //  4 MB (later reused as F1)
  unsigned short* Wb  = (unsigned short*)(ws + 8388608);    //  0.5 MB
  unsigned short* H   = (unsigned short*)(ws + 8912896);    //  8 MB (both MLP chains)
  unsigned short* F   = (unsigned short*)(ws + 0);          //  8 MB (F1 @0, F2 @4MB)
  __half* E  = (__half*)(ws + 21495808);                    // 33.83 MB fp16 (final)
  unsigned char* E8  = (unsigned char*)(ws + 55328896);     // 16.92 MB fp8 (sweep)
  unsigned char* ET8 = (unsigned char*)(ws + 72245440);     // 16.92 MB fp8 (sweep)
  float* eu  = (float*)(ws + 89161984);                     // 4 x 2064 f32
  float* ev  = (float*)(ws + 89195008);                     // 4 x 2064 f32
  unsigned* bar = (unsigned*)(ws + 89228032);               // 8 KB barrier state

  unsigned short* Xte = Xlc + 2097152;   // ws + 4 MB

  // merged fp32->bf16 conversion of all six inputs (one launch, vec4)
  k_cvt6<<<4352, 256, 0, stream>>>(x_lc, x_te, W1_lc, W2_lc, W1_te, W2_te,
                                   Xlc, Xte, Wb);

  // MLPs: lc and te chains merged via blockIdx.z (z=0: lc, z=1: te).
  k_gemm_bt<0><<<dim3(2, 64, 2), 256, 0, stream>>>(Xlc, Wb,         H, nullptr, b1_lc, b1_te,
                                                   DD, 2097152, 131072, 2097152, DD);
  k_gemm_bt<1><<<dim3(2, 64, 2), 256, 0, stream>>>(H,   Wb + 65536, F, nullptr, b2_lc, b2_te,
                                                   DD, 2097152, 131072, 2097152, DD);

  // scores -> E (fp16+fp8) and ET (fp8 only), per batch
  unsigned short* F1 = F;
  unsigned short* F2 = F + 2097152;
  const long ab = (long)NQ * DD;        // 524288
  const long ob = (long)M1 * STR;       // 4229136 (elems for fp16, bytes for fp8)
  k_gemm_bt<2><<<dim3(16, 16, NB), 256, 0, stream>>>(F1, F2, E,  E8,  nullptr, nullptr, DD, ab, ab, ob, STR);
  k_gemm_bt<3><<<dim3(16, 16, NB), 256, 0, stream>>>(F2, F1, nullptr, ET8, nullptr, nullptr, DD, ab, ab, ob, STR);

  // E dustbin row/col + ev = 1 + barrier = 0 (one launch)
  const int nfill = NB * NQ * 16 + NB * STR;  // 139328
  k_fillinit<<<(nfill + 255) / 256, 256, 0, stream>>>(E, alpha, ev, bar);

  // persistent Sinkhorn: ONE plain launch, fixed 100 iterations
  k_sink<<<PNWG, PTPB, 0, stream>>>(E8, ET8, eu, ev, alpha, bar);

  // out = E * eu * ev * (m+n)
  k_final<<<NB * M1, 256, 0, stream>>>(E, eu, ev, (float*)d_out);
}